// Round 14
// baseline (321.057 us; speedup 1.0000x reference)
//
#include <hip/hip_runtime.h>

typedef unsigned short u16;
typedef __attribute__((ext_vector_type(8))) short bf16x8;
typedef __attribute__((ext_vector_type(4))) short bf16x4;
typedef __attribute__((ext_vector_type(4))) float f32x4;

#define GP(p) ((const __attribute__((address_space(1))) void*)(unsigned long long)(p))
#define LP(p) ((__attribute__((address_space(3))) void*)(unsigned int)(unsigned long long)(p))

// B=4, T=2048, D=1024, H=16, G=4, hd=64, M=B*T=8192
#define QSCALE 0.180336879486998f
// scores bounded |s| <= 11.54 -> exp2 <= 2980: no softmax bias/max needed.

__device__ __forceinline__ u16 f2bf(float f) {
  union { float f; unsigned u; } v; v.f = f;
  unsigned r = v.u + 0x7fffu + ((v.u >> 16) & 1u);
  return (u16)(r >> 16);
}
__device__ __forceinline__ short f2bf_cvt(float f) {
  __bf16 b = (__bf16)f;
  return *reinterpret_cast<short*>(&b);
}
__device__ __forceinline__ float bf2f(u16 u) {
  union { unsigned u; float f; } v; v.u = ((unsigned)u) << 16;
  return v.f;
}

#if __has_builtin(__builtin_amdgcn_mfma_f32_16x16x16bf16_1k)
#define MFMA16(A, B, C) __builtin_amdgcn_mfma_f32_16x16x16bf16_1k((A), (B), (C), 0, 0, 0)
#elif __has_builtin(__builtin_amdgcn_mfma_f32_16x16x16_bf16)
#define MFMA16(A, B, C) __builtin_amdgcn_mfma_f32_16x16x16_bf16((A), (B), (C), 0, 0, 0)
#else
static __device__ __forceinline__ f32x4 mfma16_asm(bf16x4 a, bf16x4 b, f32x4 c) {
  asm volatile("v_mfma_f32_16x16x16_bf16 %0, %1, %2, %0" : "+v"(c) : "v"(a), "v"(b));
  return c;
}
#define MFMA16(A, B, C) mfma16_asm((A), (B), (C))
#endif

// merged prep: 0-2047 cast x; 2048-2687 cast weights; 2688-2943 RoPE; 2944 flags
__global__ void prep_kernel(const float* __restrict__ x,
                            const float* __restrict__ Wq, const float* __restrict__ Wk,
                            const float* __restrict__ Wv, const float* __restrict__ Wo,
                            u16* __restrict__ xb, u16* __restrict__ Wcat,
                            u16* __restrict__ Wob,
                            float* __restrict__ ctab, float* __restrict__ stab,
                            int* __restrict__ flags) {
  const int bid = blockIdx.x, tid = threadIdx.x;
  if (bid < 2048) {
    for (int i = bid * 256 + tid; i < 2097152; i += 2048 * 256) {
      float4 v = reinterpret_cast<const float4*>(x)[i];
      reinterpret_cast<ushort4*>(xb)[i] =
          make_ushort4(f2bf(v.x), f2bf(v.y), f2bf(v.z), f2bf(v.w));
    }
  } else if (bid < 2688) {
    for (int i = (bid - 2048) * 256 + tid; i < 655360; i += 640 * 256) {
      const float* src; u16* dst; int off;
      if (i < 262144)      { src = Wq; dst = Wcat;           off = i; }
      else if (i < 327680) { src = Wk; dst = Wcat + 1048576; off = i - 262144; }
      else if (i < 393216) { src = Wv; dst = Wcat + 1310720; off = i - 327680; }
      else                 { src = Wo; dst = Wob;            off = i - 393216; }
      float4 v = reinterpret_cast<const float4*>(src)[off];
      reinterpret_cast<ushort4*>(dst)[off] =
          make_ushort4(f2bf(v.x), f2bf(v.y), f2bf(v.z), f2bf(v.w));
    }
  } else if (bid < 2944) {
    int i = (bid - 2688) * 256 + tid;  // i = t*32 + f
    int t = i >> 5, f = i & 31;
    float inv = exp2f((float)f * (-13.287712379549449f / 32.0f));
    float ang = (float)t * inv;
    float sv, cv;
    sincosf(ang, &sv, &cv);
    ctab[i] = cv;
    stab[i] = sv;
  } else {
    if (tid < 240) flags[tid] = 0;
  }
}

// C = A[M][1024] * W[N][1024]^T, double-buffered staging; epilogue fuses
// RMSNorm+RoPE for q/k, scatters V transposed into vt[bg][d][t].
__launch_bounds__(256)
__global__ void gemm_qkv_kernel(const u16* __restrict__ A, const u16* __restrict__ W,
                                u16* __restrict__ qh, u16* __restrict__ kh,
                                u16* __restrict__ vt,
                                const float* __restrict__ qn_w, const float* __restrict__ kn_w,
                                const float* __restrict__ ctab, const float* __restrict__ stab) {
  __shared__ __align__(16) u16 As[2][128 * 64];
  __shared__ __align__(16) u16 Bs[2][128 * 64];
  const int tid = threadIdx.x;
  const int w = tid >> 6, l = tid & 63;
  const int lr = l & 15, lk = l >> 4;
  const int wr = w >> 1, wc = w & 1;
  const int m0 = blockIdx.x * 128, n0 = blockIdx.y * 128;
  const u16* ap[4];
  const u16* bp[4];
#pragma unroll
  for (int i = 0; i < 4; ++i) {
    int c = i * 256 + tid;
    ap[i] = A + (size_t)(m0 + (c >> 3)) * 1024 + (c & 7) * 8;
    bp[i] = W + (size_t)(n0 + (c >> 3)) * 1024 + (c & 7) * 8;
  }
  auto stage = [&](int buf) {
#pragma unroll
    for (int i = 0; i < 4; ++i) {
      __builtin_amdgcn_global_load_lds(GP(ap[i]),
          LP((char*)&As[0][0] + buf * 16384 + (i * 256 + (tid & ~63)) * 16), 16, 0, 0);
      __builtin_amdgcn_global_load_lds(GP(bp[i]),
          LP((char*)&Bs[0][0] + buf * 16384 + (i * 256 + (tid & ~63)) * 16), 16, 0, 0);
      ap[i] += 64; bp[i] += 64;
    }
  };
  f32x4 acc[4][4] = {};
  int cur = 0;
  stage(0);
  asm volatile("s_waitcnt vmcnt(0)" ::: "memory");
  __builtin_amdgcn_s_barrier();
  for (int k0 = 0; k0 < 1024; k0 += 64) {
    if (k0 < 960) stage(cur ^ 1);
    __builtin_amdgcn_s_setprio(1);
#pragma unroll
    for (int kk = 0; kk < 2; ++kk) {
      bf16x8 af[4], bfr[4];
#pragma unroll
      for (int fi = 0; fi < 4; ++fi)
        af[fi] = *reinterpret_cast<const bf16x8*>(
            &As[cur][(wr * 64 + fi * 16 + lr) * 64 + kk * 32 + lk * 8]);
#pragma unroll
      for (int fj = 0; fj < 4; ++fj)
        bfr[fj] = *reinterpret_cast<const bf16x8*>(
            &Bs[cur][(wc * 64 + fj * 16 + lr) * 64 + kk * 32 + lk * 8]);
#pragma unroll
      for (int fi = 0; fi < 4; ++fi)
#pragma unroll
        for (int fj = 0; fj < 4; ++fj)
          acc[fi][fj] = __builtin_amdgcn_mfma_f32_16x16x32_bf16(af[fi], bfr[fj], acc[fi][fj], 0, 0, 0);
    }
    __builtin_amdgcn_s_setprio(0);
    asm volatile("s_waitcnt vmcnt(0)" ::: "memory");
    __builtin_amdgcn_s_barrier();
    cur ^= 1;
  }
  const int ncol0 = n0 + wc * 64;
  if (ncol0 < 1280) {
    const bool isq = ncol0 < 1024;
    const float* wn = isq ? qn_w : kn_w;
    const float sc = isq ? QSCALE : 1.0f;
    float wv[4];
#pragma unroll
    for (int fj = 0; fj < 4; ++fj) wv[fj] = wn[fj * 16 + lr];
#pragma unroll
    for (int fi = 0; fi < 4; ++fi)
#pragma unroll
      for (int r = 0; r < 4; ++r) {
        float ss = 0.f;
#pragma unroll
        for (int fj = 0; fj < 4; ++fj) ss += acc[fi][fj][r] * acc[fi][fj][r];
        ss += __shfl_xor(ss, 1); ss += __shfl_xor(ss, 2);
        ss += __shfl_xor(ss, 4); ss += __shfl_xor(ss, 8);
        float rinv = rsqrtf(ss * (1.0f / 64.0f) + 1e-6f);
        int m = m0 + wr * 64 + fi * 16 + lk * 4 + r;
        int t = m & 2047, b = m >> 11;
#pragma unroll
        for (int fj = 0; fj < 4; ++fj) {
          float xn = acc[fi][fj][r] * rinv * wv[fj];
          float pr = __shfl_xor(xn, 1);
          float rot = (lr & 1) ? pr : -pr;
          int ci = t * 32 + fj * 8 + (lr >> 1);
          u16 outv = f2bf((xn * ctab[ci] + rot * stab[ci]) * sc);
          int n = ncol0 + fj * 16 + lr;
          if (isq) {
            int h = n >> 6, d = n & 63;
            qh[((size_t)((b * 16 + h) * 2048 + t)) * 64 + d] = outv;
          } else {
            int n2 = n - 1024, g = n2 >> 6, d = n2 & 63;
            kh[((size_t)((b * 4 + g) * 2048 + t)) * 64 + d] = outv;
          }
        }
      }
  } else {
#pragma unroll
    for (int fi = 0; fi < 4; ++fi)
#pragma unroll
      for (int fj = 0; fj < 4; ++fj) {
        int m = m0 + wr * 64 + fi * 16 + lk * 4;
        int b = m >> 11, t = m & 2047;
        int n2 = ncol0 + fj * 16 + lr - 1280;
        int g = n2 >> 6, d = n2 & 63;
        bf16x4 o;
#pragma unroll
        for (int r = 0; r < 4; ++r) o[r] = f2bf_cvt(acc[fi][fj][r]);
        *reinterpret_cast<bf16x4*>(&vt[((size_t)((b * 4 + g) * 64 + d)) * 2048 + t]) = o;
      }
  }
}

// flash attention: DUAL-HEAD waves (one kf/vf LDS read feeds both sibling
// heads' MFMAs -> DS bytes per work halved) + uniform KV-split blocks:
// half0 = q-tile 31-p KV [0,17); half1 = q-tile 31-p KV [17,..) + q-tile p.
// Split-tile partials (bf16 O + f32 lsum, exact in no-bias exp2 domain) merged
// in-kernel via flag protocol. Row-sum via MFMA(ones). 512 blk x 8 waves.
__launch_bounds__(512, 4)
__global__ void attn_kernel(const u16* __restrict__ qh, const u16* __restrict__ kh,
                            const u16* __restrict__ vt, u16* __restrict__ ao,
                            u16* __restrict__ part, float* __restrict__ plsum,
                            int* __restrict__ flags) {
  __shared__ __align__(16) u16 Ks[2][64 * 64];
  __shared__ __align__(16) u16 Vts[2][64 * 64];
  __shared__ int sOld;
  const int tid = threadIdx.x, w = tid >> 6, l = tid & 63;
  const int lr = l & 15, lk = l >> 4;
  const int wq = w & 3, wh = w >> 2;
  const int D = blockIdx.x;
  const int j = D >> 3;
  const int p = j & 15, half = (j >> 4) & 1;
  const int z = (D & 7) + 8 * (j >> 5);  // z = b*4+g; xcd = z&7
  const int b = z >> 2, g = z & 3;
  const int h0 = g * 4 + wh * 2;  // this wave's head pair
  const u16* Qh0 = qh + ((size_t)((b * 16 + h0) * 2048)) * 64;
  const u16* Qh1 = qh + ((size_t)((b * 16 + h0 + 1) * 2048)) * 64;
  const u16* Kb = kh + ((size_t)z * 2048) * 64;
  const u16* Vtb = vt + ((size_t)z * 64) * 2048;
  const int swz = (lr & 7) * 8;
  const int qtA = 31 - p, qtB = p;
  const int tile = z * 15 + p;  // valid for p<15

  const int r0 = tid >> 3, s0 = ((tid & 7) ^ (r0 & 7)) * 8;
  char* kd = (char*)&Ks[0][0] + (tid & ~63) * 16;
  char* vd = (char*)&Vts[0][0] + (tid & ~63) * 16;
  const u16* kp; const u16* vp;

  auto stage = [&](int buf) {
    __builtin_amdgcn_global_load_lds(GP(kp), LP(kd + buf * 8192), 16, 0, 0);
    __builtin_amdgcn_global_load_lds(GP(vp), LP(vd + buf * 8192), 16, 0, 0);
    kp += 64 * 64; vp += 64;
  };

  const u16* kbase[2];
  kbase[0] = &Ks[0][lr * 64 + ((lk * 8) ^ swz)];
  kbase[1] = &Ks[0][lr * 64 + ((32 + lk * 8) ^ swz)];
  const u16* vbase[4];
#pragma unroll
  for (int fi = 0; fi < 4; ++fi)
    vbase[fi] = &Vts[0][lr * 64 + ((fi * 16 + lk * 4) ^ swz)];

  bf16x4 ones;
#pragma unroll
  for (int r = 0; r < 4; ++r) ones[r] = (short)0x3F80;

  // process q-tile qt over KV tiles [it0, it1); complete => normalize+write,
  // else partial+merge protocol.
  auto run_seg = [&](int qt, int it0, int it1, bool complete) {
    const int q0 = qt * 64;
    const u16* QA = Qh0 + (size_t)(q0 + wq * 16) * 64;
    const u16* QB = Qh1 + (size_t)(q0 + wq * 16) * 64;
    const bf16x8 qA0 = *reinterpret_cast<const bf16x8*>(&QA[lr * 64 + lk * 8]);
    const bf16x8 qA1 = *reinterpret_cast<const bf16x8*>(&QA[lr * 64 + 32 + lk * 8]);
    const bf16x8 qB0 = *reinterpret_cast<const bf16x8*>(&QB[lr * 64 + lk * 8]);
    const bf16x8 qB1 = *reinterpret_cast<const bf16x8*>(&QB[lr * 64 + 32 + lk * 8]);
    f32x4 oacc0[4] = {}, oacc1[4] = {};
    f32x4 lacc0 = {}, lacc1 = {};
    kp = Kb + (size_t)it0 * 4096 + r0 * 64 + s0;
    vp = Vtb + (size_t)r0 * 2048 + it0 * 64 + s0;
    stage(0);
    asm volatile("s_waitcnt vmcnt(0)" ::: "memory");
    __builtin_amdgcn_s_barrier();

    auto round = [&](int it, int buf) {
      if (it + 1 < it1) stage(buf ^ 1);
      f32x4 s0a[4] = {}, s1a[4] = {};
      __builtin_amdgcn_s_setprio(1);
#pragma unroll
      for (int kk = 0; kk < 2; ++kk) {
#pragma unroll
        for (int fi = 0; fi < 4; ++fi) {
          bf16x8 kf = *reinterpret_cast<const bf16x8*>(kbase[kk] + buf * 4096 + fi * 1024);
          s0a[fi] = __builtin_amdgcn_mfma_f32_16x16x32_bf16(kf, kk ? qA1 : qA0, s0a[fi], 0, 0, 0);
          s1a[fi] = __builtin_amdgcn_mfma_f32_16x16x32_bf16(kf, kk ? qB1 : qB0, s1a[fi], 0, 0, 0);
        }
      }
      __builtin_amdgcn_s_setprio(0);
      if (it == qt) {  // causal diagonal
        int qloc = wq * 16 + lr;
#pragma unroll
        for (int fi = 0; fi < 4; ++fi)
#pragma unroll
          for (int r = 0; r < 4; ++r)
            if (fi * 16 + lk * 4 + r > qloc) { s0a[fi][r] = -1e30f; s1a[fi][r] = -1e30f; }
      }
      bf16x4 pb0[4], pb1[4];
#pragma unroll
      for (int fi = 0; fi < 4; ++fi)
#pragma unroll
        for (int r = 0; r < 4; ++r) {
          pb0[fi][r] = f2bf_cvt(exp2f(s0a[fi][r]));
          pb1[fi][r] = f2bf_cvt(exp2f(s1a[fi][r]));
        }
      __builtin_amdgcn_s_setprio(1);
#pragma unroll
      for (int fi = 0; fi < 4; ++fi) {
        lacc0 = MFMA16(ones, pb0[fi], lacc0);
        lacc1 = MFMA16(ones, pb1[fi], lacc1);
      }
#pragma unroll
      for (int fi = 0; fi < 4; ++fi)
#pragma unroll
        for (int db = 0; db < 4; ++db) {
          bf16x4 vf = *reinterpret_cast<const bf16x4*>(vbase[fi] + buf * 4096 + db * 1024);
          oacc0[db] = MFMA16(vf, pb0[fi], oacc0[db]);
          oacc1[db] = MFMA16(vf, pb1[fi], oacc1[db]);
        }
      __builtin_amdgcn_s_setprio(0);
      asm volatile("s_waitcnt vmcnt(0)" ::: "memory");
      __builtin_amdgcn_s_barrier();
    };
    for (int it = it0; it < it1; it += 2) {
      round(it, 0);
      if (it + 1 < it1) round(it + 1, 1);
    }

    const int qrow = wq * 16 + lr;
    if (complete) {
#pragma unroll
      for (int hh = 0; hh < 2; ++hh) {
        const f32x4* oacc = hh ? oacc1 : oacc0;
        float inv = 1.0f / (hh ? lacc1[0] : lacc0[0]);
#pragma unroll
        for (int db = 0; db < 4; ++db) {
          bf16x4 o;
#pragma unroll
          for (int r = 0; r < 4; ++r) o[r] = f2bf_cvt(oacc[db][r] * inv);
          *reinterpret_cast<bf16x4*>(
              &ao[((size_t)(b * 2048 + q0 + qrow)) * 1024 + (h0 + hh) * 64 + db * 16 + lk * 4]) = o;
        }
      }
    } else {
      // write own partial (bf16 O, f32 lsum)
#pragma unroll
      for (int hh = 0; hh < 2; ++hh) {
        const f32x4* oacc = hh ? oacc1 : oacc0;
        float ls = hh ? lacc1[0] : lacc0[0];
        size_t pbase = ((size_t)(tile * 2 + half) * 4 + wh * 2 + hh) * 4096;
#pragma unroll
        for (int db = 0; db < 4; ++db) {
          bf16x4 o;
#pragma unroll
          for (int r = 0; r < 4; ++r) o[r] = f2bf_cvt(oacc[db][r]);
          *reinterpret_cast<bf16x4*>(&part[pbase + qrow * 64 + db * 16 + lk * 4]) = o;
        }
        if (lk == 0)
          plsum[((size_t)(tile * 2 + half) * 4 + wh * 2 + hh) * 64 + qrow] = ls;
      }
      __syncthreads();
      __threadfence();
      if (tid == 0) sOld = atomicAdd(&flags[tile], 1);
      __syncthreads();
      if (sOld == 1) {  // we finished second: merge and write final
        __threadfence();
        const int oh = half ^ 1;
#pragma unroll
        for (int hh = 0; hh < 2; ++hh) {
          const f32x4* oacc = hh ? oacc1 : oacc0;
          float ls = hh ? lacc1[0] : lacc0[0];
          size_t obase = ((size_t)(tile * 2 + oh) * 4 + wh * 2 + hh) * 4096;
          float lo = plsum[((size_t)(tile * 2 + oh) * 4 + wh * 2 + hh) * 64 + qrow];
          float inv = 1.0f / (ls + lo);
#pragma unroll
          for (int db = 0; db < 4; ++db) {
            bf16x4 of = *reinterpret_cast<const bf16x4*>(&part[obase + qrow * 64 + db * 16 + lk * 4]);
            bf16x4 o;
#pragma unroll
            for (int r = 0; r < 4; ++r)
              o[r] = f2bf_cvt((oacc[db][r] + bf2f((u16)of[r])) * inv);
            *reinterpret_cast<bf16x4*>(
                &ao[((size_t)(b * 2048 + q0 + qrow)) * 1024 + (h0 + hh) * 64 + db * 16 + lk * 4]) = o;
          }
        }
      }
    }
  };

  if (half == 0) {
    run_seg(qtA, 0, 17, /*complete=*/p == 15);  // qtA=16 fully covered when p=15
  } else {
    if (p < 15) run_seg(qtA, 17, qtA + 1, false);
    run_seg(qtB, 0, qtB + 1, true);
  }
}

// out[M][1024] fp32 = ao[M][1024](bf16) * Wo[1024][1024]^T(bf16), dbuf staging,
// XCD-swizzled 1-D grid
__launch_bounds__(256)
__global__ void gemm_out_kernel(const u16* __restrict__ A, const u16* __restrict__ W,
                                float* __restrict__ out) {
  __shared__ __align__(16) u16 As[2][128 * 64];
  __shared__ __align__(16) u16 Bs[2][128 * 64];
  const int tid = threadIdx.x;
  const int w = tid >> 6, l = tid & 63;
  const int lr = l & 15, lk = l >> 4;
  const int wr = w >> 1, wc = w & 1;
  const int bid = blockIdx.x;
  const int m0 = (bid >> 3) * 128, n0 = (bid & 7) * 128;
  const u16* ap[4];
  const u16* bp[4];
#pragma unroll
  for (int i = 0; i < 4; ++i) {
    int c = i * 256 + tid;
    ap[i] = A + (size_t)(m0 + (c >> 3)) * 1024 + (c & 7) * 8;
    bp[i] = W + (size_t)(n0 + (c >> 3)) * 1024 + (c & 7) * 8;
  }
  auto stage = [&](int buf) {
#pragma unroll
    for (int i = 0; i < 4; ++i) {
      __builtin_amdgcn_global_load_lds(GP(ap[i]),
          LP((char*)&As[0][0] + buf * 16384 + (i * 256 + (tid & ~63)) * 16), 16, 0, 0);
      __builtin_amdgcn_global_load_lds(GP(bp[i]),
          LP((char*)&Bs[0][0] + buf * 16384 + (i * 256 + (tid & ~63)) * 16), 16, 0, 0);
      ap[i] += 64; bp[i] += 64;
    }
  };
  f32x4 acc[4][4] = {};
  int cur = 0;
  stage(0);
  asm volatile("s_waitcnt vmcnt(0)" ::: "memory");
  __builtin_amdgcn_s_barrier();
  for (int k0 = 0; k0 < 1024; k0 += 64) {
    if (k0 < 960) stage(cur ^ 1);
    __builtin_amdgcn_s_setprio(1);
#pragma unroll
    for (int kk = 0; kk < 2; ++kk) {
      bf16x8 af[4], bfr[4];
#pragma unroll
      for (int fi = 0; fi < 4; ++fi)
        af[fi] = *reinterpret_cast<const bf16x8*>(
            &As[cur][(wr * 64 + fi * 16 + lr) * 64 + kk * 32 + lk * 8]);
#pragma unroll
      for (int fj = 0; fj < 4; ++fj)
        bfr[fj] = *reinterpret_cast<const bf16x8*>(
            &Bs[cur][(wc * 64 + fj * 16 + lr) * 64 + kk * 32 + lk * 8]);
#pragma unroll
      for (int fi = 0; fi < 4; ++fi)
#pragma unroll
        for (int fj = 0; fj < 4; ++fj)
          acc[fi][fj] = __builtin_amdgcn_mfma_f32_16x16x32_bf16(af[fi], bfr[fj], acc[fi][fj], 0, 0, 0);
    }
    __builtin_amdgcn_s_setprio(0);
    asm volatile("s_waitcnt vmcnt(0)" ::: "memory");
    __builtin_amdgcn_s_barrier();
    cur ^= 1;
  }
#pragma unroll
  for (int fi = 0; fi < 4; ++fi)
#pragma unroll
    for (int fj = 0; fj < 4; ++fj)
#pragma unroll
      for (int r = 0; r < 4; ++r) {
        int m = m0 + wr * 64 + fi * 16 + lk * 4 + r;
        int n = n0 + wc * 64 + fj * 16 + lr;
        out[(size_t)m * 1024 + n] = acc[fi][fj][r];
      }
}

extern "C" void kernel_launch(void* const* d_in, const int* in_sizes, int n_in,
                              void* d_out, int out_size, void* d_ws, size_t ws_size,
                              hipStream_t stream) {
  const float* x  = (const float*)d_in[0];
  const float* Wq = (const float*)d_in[1];
  const float* Wk = (const float*)d_in[2];
  const float* Wv = (const float*)d_in[3];
  const float* Wo = (const float*)d_in[4];
  const float* qn = (const float*)d_in[5];
  const float* kn = (const float*)d_in[6];
  float* out = (float*)d_out;
  char* ws = (char*)d_ws;
  u16* xb   = (u16*)(ws);                 // 16,777,216 (dead after gemm_qkv)
  u16* Wcat = (u16*)(ws + 16777216);      //  3,145,728
  u16* Wob  = (u16*)(ws + 19922944);      //  2,097,152
  u16* qh   = (u16*)(ws + 22020096);      // 16,777,216
  u16* kh   = (u16*)(ws + 38797312);      //  4,194,304
  u16* vtb  = (u16*)(ws + 42991616);      //  4,194,304
  u16* ao   = (u16*)(ws + 47185920);      // 16,777,216 (end 63,963,136)
  float* ctab = (float*)ao;               // overwritten by attn before gemm_out
  float* stab = ctab + 65536;
  // attn split-tile partials reuse the dead xb region:
  u16* part    = (u16*)(ws);              // 240*2*4*4096 bf16 = 15,728,640
  float* plsum = (float*)(ws + 15728640); // 240*2*4*64 f32    =    491,520
  int* flags   = (int*)(ws + 63963136);   // 240 ints (zeroed each launch by prep)

  prep_kernel<<<2945, 256, 0, stream>>>(x, Wq, Wk, Wv, Wo, xb, Wcat, Wob, ctab, stab, flags);
  dim3 g1(64, 12);
  gemm_qkv_kernel<<<g1, 256, 0, stream>>>(xb, Wcat, qh, kh, vtb, qn, kn, ctab, stab);
  attn_kernel<<<512, 512, 0, stream>>>(qh, kh, vtb, ao, part, plsum, flags);
  gemm_out_kernel<<<512, 256, 0, stream>>>(ao, Wob, out);
}

// Round 15
// 152.976 us; speedup vs baseline: 2.0987x; 2.0987x over previous
//
#include <hip/hip_runtime.h>

typedef unsigned short u16;
typedef __attribute__((ext_vector_type(8))) short bf16x8;
typedef __attribute__((ext_vector_type(4))) short bf16x4;
typedef __attribute__((ext_vector_type(4))) float f32x4;

#define GP(p) ((const __attribute__((address_space(1))) void*)(unsigned long long)(p))
#define LP(p) ((__attribute__((address_space(3))) void*)(unsigned int)(unsigned long long)(p))

// B=4, T=2048, D=1024, H=16, G=4, hd=64, M=B*T=8192
#define QSCALE 0.180336879486998f
// scores bounded |s| <= 11.54 -> exp2 <= 2980: no softmax bias/max needed.

__device__ __forceinline__ u16 f2bf(float f) {
  union { float f; unsigned u; } v; v.f = f;
  unsigned r = v.u + 0x7fffu + ((v.u >> 16) & 1u);
  return (u16)(r >> 16);
}
__device__ __forceinline__ short f2bf_cvt(float f) {
  __bf16 b = (__bf16)f;
  return *reinterpret_cast<short*>(&b);
}

#if __has_builtin(__builtin_amdgcn_mfma_f32_16x16x16bf16_1k)
#define MFMA16(A, B, C) __builtin_amdgcn_mfma_f32_16x16x16bf16_1k((A), (B), (C), 0, 0, 0)
#elif __has_builtin(__builtin_amdgcn_mfma_f32_16x16x16_bf16)
#define MFMA16(A, B, C) __builtin_amdgcn_mfma_f32_16x16x16_bf16((A), (B), (C), 0, 0, 0)
#else
static __device__ __forceinline__ f32x4 mfma16_asm(bf16x4 a, bf16x4 b, f32x4 c) {
  asm volatile("v_mfma_f32_16x16x16_bf16 %0, %1, %2, %0" : "+v"(c) : "v"(a), "v"(b));
  return c;
}
#define MFMA16(A, B, C) mfma16_asm((A), (B), (C))
#endif

// merged prep: blocks 0-2047 cast x; 2048-2687 cast weights; 2688-2943 RoPE table
__global__ void prep_kernel(const float* __restrict__ x,
                            const float* __restrict__ Wq, const float* __restrict__ Wk,
                            const float* __restrict__ Wv, const float* __restrict__ Wo,
                            u16* __restrict__ xb, u16* __restrict__ Wcat,
                            u16* __restrict__ Wob,
                            float* __restrict__ ctab, float* __restrict__ stab) {
  const int bid = blockIdx.x, tid = threadIdx.x;
  if (bid < 2048) {
    for (int i = bid * 256 + tid; i < 2097152; i += 2048 * 256) {
      float4 v = reinterpret_cast<const float4*>(x)[i];
      reinterpret_cast<ushort4*>(xb)[i] =
          make_ushort4(f2bf(v.x), f2bf(v.y), f2bf(v.z), f2bf(v.w));
    }
  } else if (bid < 2688) {
    for (int i = (bid - 2048) * 256 + tid; i < 655360; i += 640 * 256) {
      const float* src; u16* dst; int off;
      if (i < 262144)      { src = Wq; dst = Wcat;           off = i; }
      else if (i < 327680) { src = Wk; dst = Wcat + 1048576; off = i - 262144; }
      else if (i < 393216) { src = Wv; dst = Wcat + 1310720; off = i - 327680; }
      else                 { src = Wo; dst = Wob;            off = i - 393216; }
      float4 v = reinterpret_cast<const float4*>(src)[off];
      reinterpret_cast<ushort4*>(dst)[off] =
          make_ushort4(f2bf(v.x), f2bf(v.y), f2bf(v.z), f2bf(v.w));
    }
  } else {
    int i = (bid - 2688) * 256 + tid;  // i = t*32 + f
    int t = i >> 5, f = i & 31;
    float inv = exp2f((float)f * (-13.287712379549449f / 32.0f));
    float ang = (float)t * inv;
    float sv, cv;
    sincosf(ang, &sv, &cv);
    ctab[i] = cv;
    stab[i] = sv;
  }
}

// C = A[M][1024] * W[N][1024]^T, double-buffered staging; epilogue fuses
// RMSNorm+RoPE for q/k, scatters V transposed into vt[bg][d][t].
// vt rows with (d>>3)&1==1 store 8B k-unit pairs SWAPPED (t^4) so the attn
// LDS V-read covers all 32 banks (conflict-free) after its read-side XOR.
__launch_bounds__(256)
__global__ void gemm_qkv_kernel(const u16* __restrict__ A, const u16* __restrict__ W,
                                u16* __restrict__ qh, u16* __restrict__ kh,
                                u16* __restrict__ vt,
                                const float* __restrict__ qn_w, const float* __restrict__ kn_w,
                                const float* __restrict__ ctab, const float* __restrict__ stab) {
  __shared__ __align__(16) u16 As[2][128 * 64];
  __shared__ __align__(16) u16 Bs[2][128 * 64];
  const int tid = threadIdx.x;
  const int w = tid >> 6, l = tid & 63;
  const int lr = l & 15, lk = l >> 4;
  const int wr = w >> 1, wc = w & 1;
  const int m0 = blockIdx.x * 128, n0 = blockIdx.y * 128;
  const u16* ap[4];
  const u16* bp[4];
#pragma unroll
  for (int i = 0; i < 4; ++i) {
    int c = i * 256 + tid;
    ap[i] = A + (size_t)(m0 + (c >> 3)) * 1024 + (c & 7) * 8;
    bp[i] = W + (size_t)(n0 + (c >> 3)) * 1024 + (c & 7) * 8;
  }
  auto stage = [&](int buf) {
#pragma unroll
    for (int i = 0; i < 4; ++i) {
      __builtin_amdgcn_global_load_lds(GP(ap[i]),
          LP((char*)&As[0][0] + buf * 16384 + (i * 256 + (tid & ~63)) * 16), 16, 0, 0);
      __builtin_amdgcn_global_load_lds(GP(bp[i]),
          LP((char*)&Bs[0][0] + buf * 16384 + (i * 256 + (tid & ~63)) * 16), 16, 0, 0);
      ap[i] += 64; bp[i] += 64;
    }
  };
  f32x4 acc[4][4] = {};
  int cur = 0;
  stage(0);
  asm volatile("s_waitcnt vmcnt(0)" ::: "memory");
  __builtin_amdgcn_s_barrier();
  for (int k0 = 0; k0 < 1024; k0 += 64) {
    if (k0 < 960) stage(cur ^ 1);
    __builtin_amdgcn_s_setprio(1);
#pragma unroll
    for (int kk = 0; kk < 2; ++kk) {
      bf16x8 af[4], bfr[4];
#pragma unroll
      for (int fi = 0; fi < 4; ++fi)
        af[fi] = *reinterpret_cast<const bf16x8*>(
            &As[cur][(wr * 64 + fi * 16 + lr) * 64 + kk * 32 + lk * 8]);
#pragma unroll
      for (int fj = 0; fj < 4; ++fj)
        bfr[fj] = *reinterpret_cast<const bf16x8*>(
            &Bs[cur][(wc * 64 + fj * 16 + lr) * 64 + kk * 32 + lk * 8]);
#pragma unroll
      for (int fi = 0; fi < 4; ++fi)
#pragma unroll
        for (int fj = 0; fj < 4; ++fj)
          acc[fi][fj] = __builtin_amdgcn_mfma_f32_16x16x32_bf16(af[fi], bfr[fj], acc[fi][fj], 0, 0, 0);
    }
    __builtin_amdgcn_s_setprio(0);
    asm volatile("s_waitcnt vmcnt(0)" ::: "memory");
    __builtin_amdgcn_s_barrier();
    cur ^= 1;
  }
  const int ncol0 = n0 + wc * 64;
  if (ncol0 < 1280) {
    const bool isq = ncol0 < 1024;
    const float* wn = isq ? qn_w : kn_w;
    const float sc = isq ? QSCALE : 1.0f;
    float wv[4];
#pragma unroll
    for (int fj = 0; fj < 4; ++fj) wv[fj] = wn[fj * 16 + lr];
#pragma unroll
    for (int fi = 0; fi < 4; ++fi)
#pragma unroll
      for (int r = 0; r < 4; ++r) {
        float ss = 0.f;
#pragma unroll
        for (int fj = 0; fj < 4; ++fj) ss += acc[fi][fj][r] * acc[fi][fj][r];
        ss += __shfl_xor(ss, 1); ss += __shfl_xor(ss, 2);
        ss += __shfl_xor(ss, 4); ss += __shfl_xor(ss, 8);
        float rinv = rsqrtf(ss * (1.0f / 64.0f) + 1e-6f);
        int m = m0 + wr * 64 + fi * 16 + lk * 4 + r;
        int t = m & 2047, b = m >> 11;
#pragma unroll
        for (int fj = 0; fj < 4; ++fj) {
          float xn = acc[fi][fj][r] * rinv * wv[fj];
          float pr = __shfl_xor(xn, 1);
          float rot = (lr & 1) ? pr : -pr;
          int ci = t * 32 + fj * 8 + (lr >> 1);
          u16 outv = f2bf((xn * ctab[ci] + rot * stab[ci]) * sc);
          int n = ncol0 + fj * 16 + lr;
          if (isq) {
            int h = n >> 6, d = n & 63;
            qh[((size_t)((b * 16 + h) * 2048 + t)) * 64 + d] = outv;
          } else {
            int n2 = n - 1024, g = n2 >> 6, d = n2 & 63;
            kh[((size_t)((b * 4 + g) * 2048 + t)) * 64 + d] = outv;
          }
        }
      }
  } else {
#pragma unroll
    for (int fi = 0; fi < 4; ++fi)
#pragma unroll
      for (int fj = 0; fj < 4; ++fj) {
        int m = m0 + wr * 64 + fi * 16 + lk * 4;
        int b = m >> 11, t = m & 2047;
        int n2 = ncol0 + fj * 16 + lr - 1280;
        int g = n2 >> 6, d = n2 & 63;
        bf16x4 o;
#pragma unroll
        for (int r = 0; r < 4; ++r) o[r] = f2bf_cvt(acc[fi][fj][r]);
        int tsw = t ^ (((d >> 3) & 1) * 4);  // pre-swap 8B k-units for odd d>>3
        *reinterpret_cast<bf16x4*>(&vt[((size_t)((b * 4 + g) * 64 + d)) * 2048 + tsw]) = o;
      }
  }
}

// flash attention: 8-wave blocks, GQA head-pair shares one K/V LDS stream.
// KVBLK=64, no softmax bias, sequential paired q-tiles (uniform 33 iters),
// dbuf staging, hoisted LDS bases + unroll-by-2. V-read bank-conflict fix:
// vt pre-swapped (gemm_qkv) + read-side ^(lr>>3)*4 -> 16 lanes cover 32 banks.
__launch_bounds__(512)
__global__ void attn_kernel(const u16* __restrict__ qh, const u16* __restrict__ kh,
                            const u16* __restrict__ vt, u16* __restrict__ ao) {
  __shared__ __align__(16) u16 Ks[2][64 * 64];
  __shared__ __align__(16) u16 Vts[2][64 * 64];
  const int tid = threadIdx.x, w = tid >> 6, l = tid & 63;
  const int lr = l & 15, lk = l >> 4;
  const int wq = w & 3, wh = w >> 2;
  // decode: xcd = D&7 selects (b,g) so all 32 blocks sharing K/V sit on 1 XCD
  const int D = blockIdx.x;
  const int j = D >> 3;
  const int p = j & 15, hp = (j >> 4) & 1;
  const int z = (D & 7) + 8 * (j >> 5);  // z = b*4+g, 0..15
  const int b = z >> 2, g = z & 3;
  const int h = g * 4 + hp * 2 + wh;
  const u16* Qh = qh + ((size_t)((b * 16 + h) * 2048)) * 64;
  const u16* Kb = kh + ((size_t)z * 2048) * 64;
  const u16* Vtb = vt + ((size_t)z * 64) * 2048;
  const int swz = (lr & 7) * 8;  // XOR swizzle in 8-elem (16B) units

  // staging: 512 threads x 16B = one 8KB tile each for K and V^T
  const int r0 = tid >> 3, s0 = ((tid & 7) ^ (r0 & 7)) * 8;
  char* kd = (char*)&Ks[0][0] + (tid & ~63) * 16;
  char* vd = (char*)&Vts[0][0] + (tid & ~63) * 16;
  const u16* kp; const u16* vp;

  auto stage = [&](int buf) {
    __builtin_amdgcn_global_load_lds(GP(kp), LP(kd + buf * 8192), 16, 0, 0);
    __builtin_amdgcn_global_load_lds(GP(vp), LP(vd + buf * 8192), 16, 0, 0);
    kp += 64 * 64; vp += 64;
  };

  // hoisted LDS read base pointers (buf0); fi/db/buf variation is an immediate
  const u16* kbase[2];
  kbase[0] = &Ks[0][lr * 64 + ((lk * 8) ^ swz)];
  kbase[1] = &Ks[0][lr * 64 + ((32 + lk * 8) ^ swz)];
  const u16* vbase[4];
#pragma unroll
  for (int fi = 0; fi < 4; ++fi)
    vbase[fi] = &Vts[0][lr * 64 + (((fi * 16 + lk * 4) ^ swz) ^ ((lr >> 3) * 4))];

  auto run_qtile = [&](int qt) {
    const int q0 = qt * 64;
    const u16* Qb = Qh + (size_t)(q0 + wq * 16) * 64;
    const bf16x8 qf0 = *reinterpret_cast<const bf16x8*>(&Qb[lr * 64 + lk * 8]);
    const bf16x8 qf1 = *reinterpret_cast<const bf16x8*>(&Qb[lr * 64 + 32 + lk * 8]);
    f32x4 oacc[4] = {};
    float lrow = 0.f;  // per-lane partial, reduced in epilogue
    kp = Kb + r0 * 64 + s0;
    vp = Vtb + (size_t)r0 * 2048 + s0;
    stage(0);
    asm volatile("s_waitcnt vmcnt(0)" ::: "memory");
    __builtin_amdgcn_s_barrier();

    auto round = [&](int it, int buf) {  // buf is a call-site literal -> folds
      if (it < qt) stage(buf ^ 1);  // prefetch next KV tile into other buffer
      // QK^T (swapped), zero-init C: sacc[fi][r] = S[k=fi*16+lk*4+r][q=lr]
      f32x4 sacc[4] = {};
      __builtin_amdgcn_s_setprio(1);
#pragma unroll
      for (int kk = 0; kk < 2; ++kk) {
        bf16x8 qf = kk ? qf1 : qf0;
#pragma unroll
        for (int fi = 0; fi < 4; ++fi) {
          bf16x8 kf = *reinterpret_cast<const bf16x8*>(kbase[kk] + buf * 4096 + fi * 1024);
          sacc[fi] = __builtin_amdgcn_mfma_f32_16x16x32_bf16(kf, qf, sacc[fi], 0, 0, 0);
        }
      }
      __builtin_amdgcn_s_setprio(0);
      if (it == qt) {  // causal mask on diagonal tile
        int qloc = wq * 16 + lr;
#pragma unroll
        for (int fi = 0; fi < 4; ++fi)
#pragma unroll
          for (int r = 0; r < 4; ++r)
            if (fi * 16 + lk * 4 + r > qloc) sacc[fi][r] = -1e30f;
      }
      // P = exp2(S); no bias, no max tracking, no per-iter reduce
      bf16x4 pb[4];
#pragma unroll
      for (int fi = 0; fi < 4; ++fi)
#pragma unroll
        for (int r = 0; r < 4; ++r) {
          float pv = exp2f(sacc[fi][r]);
          lrow += pv;
          pb[fi][r] = f2bf_cvt(pv);
        }
      // PV: A = V^T frag, B = in-register P frag, C[d][q]
      __builtin_amdgcn_s_setprio(1);
#pragma unroll
      for (int fi = 0; fi < 4; ++fi)
#pragma unroll
        for (int db = 0; db < 4; ++db) {
          bf16x4 vf = *reinterpret_cast<const bf16x4*>(vbase[fi] + buf * 4096 + db * 1024);
          oacc[db] = MFMA16(vf, pb[fi], oacc[db]);
        }
      __builtin_amdgcn_s_setprio(0);
      asm volatile("s_waitcnt vmcnt(0)" ::: "memory");  // next-tile stage landed
      __builtin_amdgcn_s_barrier();
    };

    const int nIt = qt + 1;
    for (int it = 0; it < nIt; it += 2) {
      round(it, 0);
      if (it + 1 < nIt) round(it + 1, 1);
    }

    // epilogue: complete the row-sum across lk groups (2 shuffles, once)
    float lsum = lrow;
    lsum += __shfl_xor(lsum, 16);
    lsum += __shfl_xor(lsum, 32);
    float inv = 1.0f / lsum;
#pragma unroll
    for (int db = 0; db < 4; ++db) {
      bf16x4 o;
#pragma unroll
      for (int r = 0; r < 4; ++r) o[r] = f2bf_cvt(oacc[db][r] * inv);
      *reinterpret_cast<bf16x4*>(
          &ao[((size_t)(b * 2048 + q0 + wq * 16 + lr)) * 1024 + h * 64 + db * 16 + lk * 4]) = o;
    }
  };
  run_qtile(31 - p);
  run_qtile(p);
}

// out[M][1024] fp32 = ao[M][1024](bf16) * Wo[1024][1024]^T(bf16), dbuf staging,
// XCD-swizzled 1-D grid: n-panel = bid&7 -> all blocks sharing a Wo panel on 1 XCD
__launch_bounds__(256)
__global__ void gemm_out_kernel(const u16* __restrict__ A, const u16* __restrict__ W,
                                float* __restrict__ out) {
  __shared__ __align__(16) u16 As[2][128 * 64];
  __shared__ __align__(16) u16 Bs[2][128 * 64];
  const int tid = threadIdx.x;
  const int w = tid >> 6, l = tid & 63;
  const int lr = l & 15, lk = l >> 4;
  const int wr = w >> 1, wc = w & 1;
  const int bid = blockIdx.x;
  const int m0 = (bid >> 3) * 128, n0 = (bid & 7) * 128;
  const u16* ap[4];
  const u16* bp[4];
#pragma unroll
  for (int i = 0; i < 4; ++i) {
    int c = i * 256 + tid;
    ap[i] = A + (size_t)(m0 + (c >> 3)) * 1024 + (c & 7) * 8;
    bp[i] = W + (size_t)(n0 + (c >> 3)) * 1024 + (c & 7) * 8;
  }
  auto stage = [&](int buf) {
#pragma unroll
    for (int i = 0; i < 4; ++i) {
      __builtin_amdgcn_global_load_lds(GP(ap[i]),
          LP((char*)&As[0][0] + buf * 16384 + (i * 256 + (tid & ~63)) * 16), 16, 0, 0);
      __builtin_amdgcn_global_load_lds(GP(bp[i]),
          LP((char*)&Bs[0][0] + buf * 16384 + (i * 256 + (tid & ~63)) * 16), 16, 0, 0);
      ap[i] += 64; bp[i] += 64;
    }
  };
  f32x4 acc[4][4] = {};
  int cur = 0;
  stage(0);
  asm volatile("s_waitcnt vmcnt(0)" ::: "memory");
  __builtin_amdgcn_s_barrier();
  for (int k0 = 0; k0 < 1024; k0 += 64) {
    if (k0 < 960) stage(cur ^ 1);
    __builtin_amdgcn_s_setprio(1);
#pragma unroll
    for (int kk = 0; kk < 2; ++kk) {
      bf16x8 af[4], bfr[4];
#pragma unroll
      for (int fi = 0; fi < 4; ++fi)
        af[fi] = *reinterpret_cast<const bf16x8*>(
            &As[cur][(wr * 64 + fi * 16 + lr) * 64 + kk * 32 + lk * 8]);
#pragma unroll
      for (int fj = 0; fj < 4; ++fj)
        bfr[fj] = *reinterpret_cast<const bf16x8*>(
            &Bs[cur][(wc * 64 + fj * 16 + lr) * 64 + kk * 32 + lk * 8]);
#pragma unroll
      for (int fi = 0; fi < 4; ++fi)
#pragma unroll
        for (int fj = 0; fj < 4; ++fj)
          acc[fi][fj] = __builtin_amdgcn_mfma_f32_16x16x32_bf16(af[fi], bfr[fj], acc[fi][fj], 0, 0, 0);
    }
    __builtin_amdgcn_s_setprio(0);
    asm volatile("s_waitcnt vmcnt(0)" ::: "memory");
    __builtin_amdgcn_s_barrier();
    cur ^= 1;
  }
#pragma unroll
  for (int fi = 0; fi < 4; ++fi)
#pragma unroll
    for (int fj = 0; fj < 4; ++fj)
#pragma unroll
      for (int r = 0; r < 4; ++r) {
        int m = m0 + wr * 64 + fi * 16 + lk * 4 + r;
        int n = n0 + wc * 64 + fj * 16 + lr;
        out[(size_t)m * 1024 + n] = acc[fi][fj][r];
      }
}

extern "C" void kernel_launch(void* const* d_in, const int* in_sizes, int n_in,
                              void* d_out, int out_size, void* d_ws, size_t ws_size,
                              hipStream_t stream) {
  const float* x  = (const float*)d_in[0];
  const float* Wq = (const float*)d_in[1];
  const float* Wk = (const float*)d_in[2];
  const float* Wv = (const float*)d_in[3];
  const float* Wo = (const float*)d_in[4];
  const float* qn = (const float*)d_in[5];
  const float* kn = (const float*)d_in[6];
  float* out = (float*)d_out;
  char* ws = (char*)d_ws;
  u16* xb   = (u16*)(ws);                 // 16,777,216
  u16* Wcat = (u16*)(ws + 16777216);      //  3,145,728
  u16* Wob  = (u16*)(ws + 19922944);      //  2,097,152
  u16* qh   = (u16*)(ws + 22020096);      // 16,777,216
  u16* kh   = (u16*)(ws + 38797312);      //  4,194,304
  u16* vtb  = (u16*)(ws + 42991616);      //  4,194,304
  u16* ao   = (u16*)(ws + 47185920);      // 16,777,216 (end 63,963,136)
  float* ctab = (float*)ao;               // overwritten by attn before gemm_out
  float* stab = ctab + 65536;

  prep_kernel<<<2944, 256, 0, stream>>>(x, Wq, Wk, Wv, Wo, xb, Wcat, Wob, ctab, stab);
  dim3 g1(64, 12);
  gemm_qkv_kernel<<<g1, 256, 0, stream>>>(xb, Wcat, qh, kh, vtb, qn, kn, ctab, stab);
  attn_kernel<<<512, 512, 0, stream>>>(qh, kh, vtb, ao);
  gemm_out_kernel<<<512, 256, 0, stream>>>(ao, Wob, out);
}

// Round 16
// 150.685 us; speedup vs baseline: 2.1307x; 1.0152x over previous
//
#include <hip/hip_runtime.h>

typedef unsigned short u16;
typedef __attribute__((ext_vector_type(8))) short bf16x8;
typedef __attribute__((ext_vector_type(4))) short bf16x4;
typedef __attribute__((ext_vector_type(4))) float f32x4;

#define GP(p) ((const __attribute__((address_space(1))) void*)(unsigned long long)(p))
#define LP(p) ((__attribute__((address_space(3))) void*)(unsigned int)(unsigned long long)(p))

// B=4, T=2048, D=1024, H=16, G=4, hd=64, M=B*T=8192
#define QSCALE 0.180336879486998f
// scores bounded |s| <= 11.54 -> exp2 <= 2980: no softmax bias/max needed.

__device__ __forceinline__ u16 f2bf(float f) {
  union { float f; unsigned u; } v; v.f = f;
  unsigned r = v.u + 0x7fffu + ((v.u >> 16) & 1u);
  return (u16)(r >> 16);
}
__device__ __forceinline__ short f2bf_cvt(float f) {
  __bf16 b = (__bf16)f;
  return *reinterpret_cast<short*>(&b);
}

#if __has_builtin(__builtin_amdgcn_mfma_f32_16x16x16bf16_1k)
#define MFMA16(A, B, C) __builtin_amdgcn_mfma_f32_16x16x16bf16_1k((A), (B), (C), 0, 0, 0)
#elif __has_builtin(__builtin_amdgcn_mfma_f32_16x16x16_bf16)
#define MFMA16(A, B, C) __builtin_amdgcn_mfma_f32_16x16x16_bf16((A), (B), (C), 0, 0, 0)
#else
static __device__ __forceinline__ f32x4 mfma16_asm(bf16x4 a, bf16x4 b, f32x4 c) {
  asm volatile("v_mfma_f32_16x16x16_bf16 %0, %1, %2, %0" : "+v"(c) : "v"(a), "v"(b));
  return c;
}
#define MFMA16(A, B, C) mfma16_asm((A), (B), (C))
#endif

// merged prep: blocks 0-2047 cast x; 2048-2687 cast weights; 2688-2943 RoPE table
__global__ void prep_kernel(const float* __restrict__ x,
                            const float* __restrict__ Wq, const float* __restrict__ Wk,
                            const float* __restrict__ Wv, const float* __restrict__ Wo,
                            u16* __restrict__ xb, u16* __restrict__ Wcat,
                            u16* __restrict__ Wob,
                            float* __restrict__ ctab, float* __restrict__ stab) {
  const int bid = blockIdx.x, tid = threadIdx.x;
  if (bid < 2048) {
    for (int i = bid * 256 + tid; i < 2097152; i += 2048 * 256) {
      float4 v = reinterpret_cast<const float4*>(x)[i];
      reinterpret_cast<ushort4*>(xb)[i] =
          make_ushort4(f2bf(v.x), f2bf(v.y), f2bf(v.z), f2bf(v.w));
    }
  } else if (bid < 2688) {
    for (int i = (bid - 2048) * 256 + tid; i < 655360; i += 640 * 256) {
      const float* src; u16* dst; int off;
      if (i < 262144)      { src = Wq; dst = Wcat;           off = i; }
      else if (i < 327680) { src = Wk; dst = Wcat + 1048576; off = i - 262144; }
      else if (i < 393216) { src = Wv; dst = Wcat + 1310720; off = i - 327680; }
      else                 { src = Wo; dst = Wob;            off = i - 393216; }
      float4 v = reinterpret_cast<const float4*>(src)[off];
      reinterpret_cast<ushort4*>(dst)[off] =
          make_ushort4(f2bf(v.x), f2bf(v.y), f2bf(v.z), f2bf(v.w));
    }
  } else {
    int i = (bid - 2688) * 256 + tid;  // i = t*32 + f
    int t = i >> 5, f = i & 31;
    float inv = exp2f((float)f * (-13.287712379549449f / 32.0f));
    float ang = (float)t * inv;
    float sv, cv;
    sincosf(ang, &sv, &cv);
    ctab[i] = cv;
    stab[i] = sv;
  }
}

// C = A[M][1024] * W[N][1024]^T, double-buffered staging; epilogue fuses
// RMSNorm+RoPE for q/k, scatters V transposed into vt[bg][d][t].
// vt rows with (d>>3)&1==1 store 8B k-unit pairs SWAPPED (t^4) so the attn
// LDS V-read covers all 32 banks (conflict-free) after its read-side XOR.
__launch_bounds__(256)
__global__ void gemm_qkv_kernel(const u16* __restrict__ A, const u16* __restrict__ W,
                                u16* __restrict__ qh, u16* __restrict__ kh,
                                u16* __restrict__ vt,
                                const float* __restrict__ qn_w, const float* __restrict__ kn_w,
                                const float* __restrict__ ctab, const float* __restrict__ stab) {
  __shared__ __align__(16) u16 As[2][128 * 64];
  __shared__ __align__(16) u16 Bs[2][128 * 64];
  const int tid = threadIdx.x;
  const int w = tid >> 6, l = tid & 63;
  const int lr = l & 15, lk = l >> 4;
  const int wr = w >> 1, wc = w & 1;
  const int m0 = blockIdx.x * 128, n0 = blockIdx.y * 128;
  const u16* ap[4];
  const u16* bp[4];
#pragma unroll
  for (int i = 0; i < 4; ++i) {
    int c = i * 256 + tid;
    ap[i] = A + (size_t)(m0 + (c >> 3)) * 1024 + (c & 7) * 8;
    bp[i] = W + (size_t)(n0 + (c >> 3)) * 1024 + (c & 7) * 8;
  }
  auto stage = [&](int buf) {
#pragma unroll
    for (int i = 0; i < 4; ++i) {
      __builtin_amdgcn_global_load_lds(GP(ap[i]),
          LP((char*)&As[0][0] + buf * 16384 + (i * 256 + (tid & ~63)) * 16), 16, 0, 0);
      __builtin_amdgcn_global_load_lds(GP(bp[i]),
          LP((char*)&Bs[0][0] + buf * 16384 + (i * 256 + (tid & ~63)) * 16), 16, 0, 0);
      ap[i] += 64; bp[i] += 64;
    }
  };
  f32x4 acc[4][4] = {};
  int cur = 0;
  stage(0);
  asm volatile("s_waitcnt vmcnt(0)" ::: "memory");
  __builtin_amdgcn_s_barrier();
  for (int k0 = 0; k0 < 1024; k0 += 64) {
    if (k0 < 960) stage(cur ^ 1);
    __builtin_amdgcn_s_setprio(1);
#pragma unroll
    for (int kk = 0; kk < 2; ++kk) {
      bf16x8 af[4], bfr[4];
#pragma unroll
      for (int fi = 0; fi < 4; ++fi)
        af[fi] = *reinterpret_cast<const bf16x8*>(
            &As[cur][(wr * 64 + fi * 16 + lr) * 64 + kk * 32 + lk * 8]);
#pragma unroll
      for (int fj = 0; fj < 4; ++fj)
        bfr[fj] = *reinterpret_cast<const bf16x8*>(
            &Bs[cur][(wc * 64 + fj * 16 + lr) * 64 + kk * 32 + lk * 8]);
#pragma unroll
      for (int fi = 0; fi < 4; ++fi)
#pragma unroll
        for (int fj = 0; fj < 4; ++fj)
          acc[fi][fj] = __builtin_amdgcn_mfma_f32_16x16x32_bf16(af[fi], bfr[fj], acc[fi][fj], 0, 0, 0);
    }
    __builtin_amdgcn_s_setprio(0);
    asm volatile("s_waitcnt vmcnt(0)" ::: "memory");
    __builtin_amdgcn_s_barrier();
    cur ^= 1;
  }
  const int ncol0 = n0 + wc * 64;
  if (ncol0 < 1280) {
    const bool isq = ncol0 < 1024;
    const float* wn = isq ? qn_w : kn_w;
    const float sc = isq ? QSCALE : 1.0f;
    float wv[4];
#pragma unroll
    for (int fj = 0; fj < 4; ++fj) wv[fj] = wn[fj * 16 + lr];
#pragma unroll
    for (int fi = 0; fi < 4; ++fi)
#pragma unroll
      for (int r = 0; r < 4; ++r) {
        float ss = 0.f;
#pragma unroll
        for (int fj = 0; fj < 4; ++fj) ss += acc[fi][fj][r] * acc[fi][fj][r];
        ss += __shfl_xor(ss, 1); ss += __shfl_xor(ss, 2);
        ss += __shfl_xor(ss, 4); ss += __shfl_xor(ss, 8);
        float rinv = rsqrtf(ss * (1.0f / 64.0f) + 1e-6f);
        int m = m0 + wr * 64 + fi * 16 + lk * 4 + r;
        int t = m & 2047, b = m >> 11;
#pragma unroll
        for (int fj = 0; fj < 4; ++fj) {
          float xn = acc[fi][fj][r] * rinv * wv[fj];
          float pr = __shfl_xor(xn, 1);
          float rot = (lr & 1) ? pr : -pr;
          int ci = t * 32 + fj * 8 + (lr >> 1);
          u16 outv = f2bf((xn * ctab[ci] + rot * stab[ci]) * sc);
          int n = ncol0 + fj * 16 + lr;
          if (isq) {
            int h = n >> 6, d = n & 63;
            qh[((size_t)((b * 16 + h) * 2048 + t)) * 64 + d] = outv;
          } else {
            int n2 = n - 1024, g = n2 >> 6, d = n2 & 63;
            kh[((size_t)((b * 4 + g) * 2048 + t)) * 64 + d] = outv;
          }
        }
      }
  } else {
#pragma unroll
    for (int fi = 0; fi < 4; ++fi)
#pragma unroll
      for (int fj = 0; fj < 4; ++fj) {
        int m = m0 + wr * 64 + fi * 16 + lk * 4;
        int b = m >> 11, t = m & 2047;
        int n2 = ncol0 + fj * 16 + lr - 1280;
        int g = n2 >> 6, d = n2 & 63;
        bf16x4 o;
#pragma unroll
        for (int r = 0; r < 4; ++r) o[r] = f2bf_cvt(acc[fi][fj][r]);
        int tsw = t ^ (((d >> 3) & 1) * 4);  // pre-swap 8B k-units for odd d>>3
        *reinterpret_cast<bf16x4*>(&vt[((size_t)((b * 4 + g) * 64 + d)) * 2048 + tsw]) = o;
      }
  }
}

// flash attention: 8-wave blocks, GQA head-pair shares one K/V LDS stream.
// KVBLK=64, no softmax bias, sequential paired q-tiles (uniform 33 iters),
// dbuf staging, hoisted LDS bases + unroll-by-2, conflict-free K and V reads.
// Row-sum via MFMA(A=ones): lacc[0] = full softmax denominator (replaces 16
// VALU adds/iter + 2 epilogue shuffles with 4 MFMA16/iter on the idle pipe).
__launch_bounds__(512)
__global__ void attn_kernel(const u16* __restrict__ qh, const u16* __restrict__ kh,
                            const u16* __restrict__ vt, u16* __restrict__ ao) {
  __shared__ __align__(16) u16 Ks[2][64 * 64];
  __shared__ __align__(16) u16 Vts[2][64 * 64];
  const int tid = threadIdx.x, w = tid >> 6, l = tid & 63;
  const int lr = l & 15, lk = l >> 4;
  const int wq = w & 3, wh = w >> 2;
  // decode: xcd = D&7 selects (b,g) so all 32 blocks sharing K/V sit on 1 XCD
  const int D = blockIdx.x;
  const int j = D >> 3;
  const int p = j & 15, hp = (j >> 4) & 1;
  const int z = (D & 7) + 8 * (j >> 5);  // z = b*4+g, 0..15
  const int b = z >> 2, g = z & 3;
  const int h = g * 4 + hp * 2 + wh;
  const u16* Qh = qh + ((size_t)((b * 16 + h) * 2048)) * 64;
  const u16* Kb = kh + ((size_t)z * 2048) * 64;
  const u16* Vtb = vt + ((size_t)z * 64) * 2048;
  const int swz = (lr & 7) * 8;  // XOR swizzle in 8-elem (16B) units

  // staging: 512 threads x 16B = one 8KB tile each for K and V^T
  const int r0 = tid >> 3, s0 = ((tid & 7) ^ (r0 & 7)) * 8;
  char* kd = (char*)&Ks[0][0] + (tid & ~63) * 16;
  char* vd = (char*)&Vts[0][0] + (tid & ~63) * 16;
  const u16* kp; const u16* vp;

  auto stage = [&](int buf) {
    __builtin_amdgcn_global_load_lds(GP(kp), LP(kd + buf * 8192), 16, 0, 0);
    __builtin_amdgcn_global_load_lds(GP(vp), LP(vd + buf * 8192), 16, 0, 0);
    kp += 64 * 64; vp += 64;
  };

  // hoisted LDS read base pointers (buf0); fi/db/buf variation is an immediate
  const u16* kbase[2];
  kbase[0] = &Ks[0][lr * 64 + ((lk * 8) ^ swz)];
  kbase[1] = &Ks[0][lr * 64 + ((32 + lk * 8) ^ swz)];
  const u16* vbase[4];
#pragma unroll
  for (int fi = 0; fi < 4; ++fi)
    vbase[fi] = &Vts[0][lr * 64 + (((fi * 16 + lk * 4) ^ swz) ^ ((lr >> 3) * 4))];

  bf16x4 ones;
#pragma unroll
  for (int r = 0; r < 4; ++r) ones[r] = (short)0x3F80;  // bf16 1.0

  auto run_qtile = [&](int qt) {
    const int q0 = qt * 64;
    const u16* Qb = Qh + (size_t)(q0 + wq * 16) * 64;
    const bf16x8 qf0 = *reinterpret_cast<const bf16x8*>(&Qb[lr * 64 + lk * 8]);
    const bf16x8 qf1 = *reinterpret_cast<const bf16x8*>(&Qb[lr * 64 + 32 + lk * 8]);
    f32x4 oacc[4] = {};
    f32x4 lacc = {};  // row-sum accumulator via MFMA(ones)
    kp = Kb + r0 * 64 + s0;
    vp = Vtb + (size_t)r0 * 2048 + s0;
    stage(0);
    asm volatile("s_waitcnt vmcnt(0)" ::: "memory");
    __builtin_amdgcn_s_barrier();

    auto round = [&](int it, int buf) {  // buf is a call-site literal -> folds
      if (it < qt) stage(buf ^ 1);  // prefetch next KV tile into other buffer
      // QK^T (swapped), zero-init C: sacc[fi][r] = S[k=fi*16+lk*4+r][q=lr]
      f32x4 sacc[4] = {};
      __builtin_amdgcn_s_setprio(1);
#pragma unroll
      for (int kk = 0; kk < 2; ++kk) {
        bf16x8 qf = kk ? qf1 : qf0;
#pragma unroll
        for (int fi = 0; fi < 4; ++fi) {
          bf16x8 kf = *reinterpret_cast<const bf16x8*>(kbase[kk] + buf * 4096 + fi * 1024);
          sacc[fi] = __builtin_amdgcn_mfma_f32_16x16x32_bf16(kf, qf, sacc[fi], 0, 0, 0);
        }
      }
      __builtin_amdgcn_s_setprio(0);
      if (it == qt) {  // causal mask on diagonal tile
        int qloc = wq * 16 + lr;
#pragma unroll
        for (int fi = 0; fi < 4; ++fi)
#pragma unroll
          for (int r = 0; r < 4; ++r)
            if (fi * 16 + lk * 4 + r > qloc) sacc[fi][r] = -1e30f;
      }
      // P = exp2(S); no bias, no max tracking; row-sum via MFMA below
      bf16x4 pb[4];
#pragma unroll
      for (int fi = 0; fi < 4; ++fi)
#pragma unroll
        for (int r = 0; r < 4; ++r)
          pb[fi][r] = f2bf_cvt(exp2f(sacc[fi][r]));
      // PV + row-sum: A = V^T frag / ones, B = in-register P frag
      __builtin_amdgcn_s_setprio(1);
#pragma unroll
      for (int fi = 0; fi < 4; ++fi) {
        lacc = MFMA16(ones, pb[fi], lacc);
#pragma unroll
        for (int db = 0; db < 4; ++db) {
          bf16x4 vf = *reinterpret_cast<const bf16x4*>(vbase[fi] + buf * 4096 + db * 1024);
          oacc[db] = MFMA16(vf, pb[fi], oacc[db]);
        }
      }
      __builtin_amdgcn_s_setprio(0);
      asm volatile("s_waitcnt vmcnt(0)" ::: "memory");  // next-tile stage landed
      __builtin_amdgcn_s_barrier();
    };

    const int nIt = qt + 1;
    for (int it = 0; it < nIt; it += 2) {
      round(it, 0);
      if (it + 1 < nIt) round(it + 1, 1);
    }

    // lacc[0] = full row-sum for q=lr (summed over all k incl. lk groups)
    float inv = 1.0f / lacc[0];
#pragma unroll
    for (int db = 0; db < 4; ++db) {
      bf16x4 o;
#pragma unroll
      for (int r = 0; r < 4; ++r) o[r] = f2bf_cvt(oacc[db][r] * inv);
      *reinterpret_cast<bf16x4*>(
          &ao[((size_t)(b * 2048 + q0 + wq * 16 + lr)) * 1024 + h * 64 + db * 16 + lk * 4]) = o;
    }
  };
  run_qtile(31 - p);
  run_qtile(p);
}

// out[M][1024] fp32 = ao[M][1024](bf16) * Wo[1024][1024]^T(bf16), dbuf staging,
// XCD-swizzled 1-D grid: n-panel = bid&7 -> all blocks sharing a Wo panel on 1 XCD
__launch_bounds__(256)
__global__ void gemm_out_kernel(const u16* __restrict__ A, const u16* __restrict__ W,
                                float* __restrict__ out) {
  __shared__ __align__(16) u16 As[2][128 * 64];
  __shared__ __align__(16) u16 Bs[2][128 * 64];
  const int tid = threadIdx.x;
  const int w = tid >> 6, l = tid & 63;
  const int lr = l & 15, lk = l >> 4;
  const int wr = w >> 1, wc = w & 1;
  const int bid = blockIdx.x;
  const int m0 = (bid >> 3) * 128, n0 = (bid & 7) * 128;
  const u16* ap[4];
  const u16* bp[4];
#pragma unroll
  for (int i = 0; i < 4; ++i) {
    int c = i * 256 + tid;
    ap[i] = A + (size_t)(m0 + (c >> 3)) * 1024 + (c & 7) * 8;
    bp[i] = W + (size_t)(n0 + (c >> 3)) * 1024 + (c & 7) * 8;
  }
  auto stage = [&](int buf) {
#pragma unroll
    for (int i = 0; i < 4; ++i) {
      __builtin_amdgcn_global_load_lds(GP(ap[i]),
          LP((char*)&As[0][0] + buf * 16384 + (i * 256 + (tid & ~63)) * 16), 16, 0, 0);
      __builtin_amdgcn_global_load_lds(GP(bp[i]),
          LP((char*)&Bs[0][0] + buf * 16384 + (i * 256 + (tid & ~63)) * 16), 16, 0, 0);
      ap[i] += 64; bp[i] += 64;
    }
  };
  f32x4 acc[4][4] = {};
  int cur = 0;
  stage(0);
  asm volatile("s_waitcnt vmcnt(0)" ::: "memory");
  __builtin_amdgcn_s_barrier();
  for (int k0 = 0; k0 < 1024; k0 += 64) {
    if (k0 < 960) stage(cur ^ 1);
    __builtin_amdgcn_s_setprio(1);
#pragma unroll
    for (int kk = 0; kk < 2; ++kk) {
      bf16x8 af[4], bfr[4];
#pragma unroll
      for (int fi = 0; fi < 4; ++fi)
        af[fi] = *reinterpret_cast<const bf16x8*>(
            &As[cur][(wr * 64 + fi * 16 + lr) * 64 + kk * 32 + lk * 8]);
#pragma unroll
      for (int fj = 0; fj < 4; ++fj)
        bfr[fj] = *reinterpret_cast<const bf16x8*>(
            &Bs[cur][(wc * 64 + fj * 16 + lr) * 64 + kk * 32 + lk * 8]);
#pragma unroll
      for (int fi = 0; fi < 4; ++fi)
#pragma unroll
        for (int fj = 0; fj < 4; ++fj)
          acc[fi][fj] = __builtin_amdgcn_mfma_f32_16x16x32_bf16(af[fi], bfr[fj], acc[fi][fj], 0, 0, 0);
    }
    __builtin_amdgcn_s_setprio(0);
    asm volatile("s_waitcnt vmcnt(0)" ::: "memory");
    __builtin_amdgcn_s_barrier();
    cur ^= 1;
  }
#pragma unroll
  for (int fi = 0; fi < 4; ++fi)
#pragma unroll
    for (int fj = 0; fj < 4; ++fj)
#pragma unroll
      for (int r = 0; r < 4; ++r) {
        int m = m0 + wr * 64 + fi * 16 + lk * 4 + r;
        int n = n0 + wc * 64 + fj * 16 + lr;
        out[(size_t)m * 1024 + n] = acc[fi][fj][r];
      }
}

extern "C" void kernel_launch(void* const* d_in, const int* in_sizes, int n_in,
                              void* d_out, int out_size, void* d_ws, size_t ws_size,
                              hipStream_t stream) {
  const float* x  = (const float*)d_in[0];
  const float* Wq = (const float*)d_in[1];
  const float* Wk = (const float*)d_in[2];
  const float* Wv = (const float*)d_in[3];
  const float* Wo = (const float*)d_in[4];
  const float* qn = (const float*)d_in[5];
  const float* kn = (const float*)d_in[6];
  float* out = (float*)d_out;
  char* ws = (char*)d_ws;
  u16* xb   = (u16*)(ws);                 // 16,777,216
  u16* Wcat = (u16*)(ws + 16777216);      //  3,145,728
  u16* Wob  = (u16*)(ws + 19922944);      //  2,097,152
  u16* qh   = (u16*)(ws + 22020096);      // 16,777,216
  u16* kh   = (u16*)(ws + 38797312);      //  4,194,304
  u16* vtb  = (u16*)(ws + 42991616);      //  4,194,304
  u16* ao   = (u16*)(ws + 47185920);      // 16,777,216 (end 63,963,136)
  float* ctab = (float*)ao;               // overwritten by attn before gemm_out
  float* stab = ctab + 65536;

  prep_kernel<<<2944, 256, 0, stream>>>(x, Wq, Wk, Wv, Wo, xb, Wcat, Wob, ctab, stab);
  dim3 g1(64, 12);
  gemm_qkv_kernel<<<g1, 256, 0, stream>>>(xb, Wcat, qh, kh, vtb, qn, kn, ctab, stab);
  attn_kernel<<<512, 512, 0, stream>>>(qh, kh, vtb, ao);
  gemm_out_kernel<<<512, 256, 0, stream>>>(ao, Wob, out);
}

// Round 17
// 149.771 us; speedup vs baseline: 2.1437x; 1.0061x over previous
//
#include <hip/hip_runtime.h>

typedef unsigned short u16;
typedef __attribute__((ext_vector_type(8))) short bf16x8;
typedef __attribute__((ext_vector_type(4))) short bf16x4;
typedef __attribute__((ext_vector_type(4))) float f32x4;

#define GP(p) ((const __attribute__((address_space(1))) void*)(unsigned long long)(p))
#define LP(p) ((__attribute__((address_space(3))) void*)(unsigned int)(unsigned long long)(p))

// B=4, T=2048, D=1024, H=16, G=4, hd=64, M=B*T=8192
#define QSCALE 0.180336879486998f
// scores bounded |s| <= 11.54 -> exp2 <= 2980: no softmax bias/max needed.

__device__ __forceinline__ u16 f2bf(float f) {
  union { float f; unsigned u; } v; v.f = f;
  unsigned r = v.u + 0x7fffu + ((v.u >> 16) & 1u);
  return (u16)(r >> 16);
}
__device__ __forceinline__ short f2bf_cvt(float f) {
  __bf16 b = (__bf16)f;
  return *reinterpret_cast<short*>(&b);
}

#if __has_builtin(__builtin_amdgcn_mfma_f32_16x16x16bf16_1k)
#define MFMA16(A, B, C) __builtin_amdgcn_mfma_f32_16x16x16bf16_1k((A), (B), (C), 0, 0, 0)
#elif __has_builtin(__builtin_amdgcn_mfma_f32_16x16x16_bf16)
#define MFMA16(A, B, C) __builtin_amdgcn_mfma_f32_16x16x16_bf16((A), (B), (C), 0, 0, 0)
#else
static __device__ __forceinline__ f32x4 mfma16_asm(bf16x4 a, bf16x4 b, f32x4 c) {
  asm volatile("v_mfma_f32_16x16x16_bf16 %0, %1, %2, %0" : "+v"(c) : "v"(a), "v"(b));
  return c;
}
#define MFMA16(A, B, C) mfma16_asm((A), (B), (C))
#endif

// merged prep: blocks 0-2047 cast x; 2048-2687 cast weights; 2688-2943 RoPE table
__global__ void prep_kernel(const float* __restrict__ x,
                            const float* __restrict__ Wq, const float* __restrict__ Wk,
                            const float* __restrict__ Wv, const float* __restrict__ Wo,
                            u16* __restrict__ xb, u16* __restrict__ Wcat,
                            u16* __restrict__ Wob,
                            float* __restrict__ ctab, float* __restrict__ stab) {
  const int bid = blockIdx.x, tid = threadIdx.x;
  if (bid < 2048) {
    for (int i = bid * 256 + tid; i < 2097152; i += 2048 * 256) {
      float4 v = reinterpret_cast<const float4*>(x)[i];
      reinterpret_cast<ushort4*>(xb)[i] =
          make_ushort4(f2bf(v.x), f2bf(v.y), f2bf(v.z), f2bf(v.w));
    }
  } else if (bid < 2688) {
    for (int i = (bid - 2048) * 256 + tid; i < 655360; i += 640 * 256) {
      const float* src; u16* dst; int off;
      if (i < 262144)      { src = Wq; dst = Wcat;           off = i; }
      else if (i < 327680) { src = Wk; dst = Wcat + 1048576; off = i - 262144; }
      else if (i < 393216) { src = Wv; dst = Wcat + 1310720; off = i - 327680; }
      else                 { src = Wo; dst = Wob;            off = i - 393216; }
      float4 v = reinterpret_cast<const float4*>(src)[off];
      reinterpret_cast<ushort4*>(dst)[off] =
          make_ushort4(f2bf(v.x), f2bf(v.y), f2bf(v.z), f2bf(v.w));
    }
  } else {
    int i = (bid - 2688) * 256 + tid;  // i = t*32 + f
    int t = i >> 5, f = i & 31;
    float inv = exp2f((float)f * (-13.287712379549449f / 32.0f));
    float ang = (float)t * inv;
    float sv, cv;
    sincosf(ang, &sv, &cv);
    ctab[i] = cv;
    stab[i] = sv;
  }
}

// C = A[M][1024] * W[N][1024]^T, double-buffered staging; epilogue fuses
// RMSNorm+RoPE for q/k, scatters V transposed into vt[bg][d][t].
// vt rows with (d>>3)&1==1 store 8B k-unit pairs SWAPPED (t^4) so the attn
// LDS V-read covers all 32 banks (conflict-free) after its read-side XOR.
__launch_bounds__(256)
__global__ void gemm_qkv_kernel(const u16* __restrict__ A, const u16* __restrict__ W,
                                u16* __restrict__ qh, u16* __restrict__ kh,
                                u16* __restrict__ vt,
                                const float* __restrict__ qn_w, const float* __restrict__ kn_w,
                                const float* __restrict__ ctab, const float* __restrict__ stab) {
  __shared__ __align__(16) u16 As[2][128 * 64];
  __shared__ __align__(16) u16 Bs[2][128 * 64];
  const int tid = threadIdx.x;
  const int w = tid >> 6, l = tid & 63;
  const int lr = l & 15, lk = l >> 4;
  const int wr = w >> 1, wc = w & 1;
  const int m0 = blockIdx.x * 128, n0 = blockIdx.y * 128;
  const u16* ap[4];
  const u16* bp[4];
#pragma unroll
  for (int i = 0; i < 4; ++i) {
    int c = i * 256 + tid;
    ap[i] = A + (size_t)(m0 + (c >> 3)) * 1024 + (c & 7) * 8;
    bp[i] = W + (size_t)(n0 + (c >> 3)) * 1024 + (c & 7) * 8;
  }
  auto stage = [&](int buf) {
#pragma unroll
    for (int i = 0; i < 4; ++i) {
      __builtin_amdgcn_global_load_lds(GP(ap[i]),
          LP((char*)&As[0][0] + buf * 16384 + (i * 256 + (tid & ~63)) * 16), 16, 0, 0);
      __builtin_amdgcn_global_load_lds(GP(bp[i]),
          LP((char*)&Bs[0][0] + buf * 16384 + (i * 256 + (tid & ~63)) * 16), 16, 0, 0);
      ap[i] += 64; bp[i] += 64;
    }
  };
  f32x4 acc[4][4] = {};
  int cur = 0;
  stage(0);
  asm volatile("s_waitcnt vmcnt(0)" ::: "memory");
  __builtin_amdgcn_s_barrier();
  for (int k0 = 0; k0 < 1024; k0 += 64) {
    if (k0 < 960) stage(cur ^ 1);
    __builtin_amdgcn_s_setprio(1);
#pragma unroll
    for (int kk = 0; kk < 2; ++kk) {
      bf16x8 af[4], bfr[4];
#pragma unroll
      for (int fi = 0; fi < 4; ++fi)
        af[fi] = *reinterpret_cast<const bf16x8*>(
            &As[cur][(wr * 64 + fi * 16 + lr) * 64 + kk * 32 + lk * 8]);
#pragma unroll
      for (int fj = 0; fj < 4; ++fj)
        bfr[fj] = *reinterpret_cast<const bf16x8*>(
            &Bs[cur][(wc * 64 + fj * 16 + lr) * 64 + kk * 32 + lk * 8]);
#pragma unroll
      for (int fi = 0; fi < 4; ++fi)
#pragma unroll
        for (int fj = 0; fj < 4; ++fj)
          acc[fi][fj] = __builtin_amdgcn_mfma_f32_16x16x32_bf16(af[fi], bfr[fj], acc[fi][fj], 0, 0, 0);
    }
    __builtin_amdgcn_s_setprio(0);
    asm volatile("s_waitcnt vmcnt(0)" ::: "memory");
    __builtin_amdgcn_s_barrier();
    cur ^= 1;
  }
  const int ncol0 = n0 + wc * 64;
  if (ncol0 < 1280) {
    const bool isq = ncol0 < 1024;
    const float* wn = isq ? qn_w : kn_w;
    const float sc = isq ? QSCALE : 1.0f;
    float wv[4];
#pragma unroll
    for (int fj = 0; fj < 4; ++fj) wv[fj] = wn[fj * 16 + lr];
#pragma unroll
    for (int fi = 0; fi < 4; ++fi)
#pragma unroll
      for (int r = 0; r < 4; ++r) {
        float ss = 0.f;
#pragma unroll
        for (int fj = 0; fj < 4; ++fj) ss += acc[fi][fj][r] * acc[fi][fj][r];
        ss += __shfl_xor(ss, 1); ss += __shfl_xor(ss, 2);
        ss += __shfl_xor(ss, 4); ss += __shfl_xor(ss, 8);
        float rinv = rsqrtf(ss * (1.0f / 64.0f) + 1e-6f);
        int m = m0 + wr * 64 + fi * 16 + lk * 4 + r;
        int t = m & 2047, b = m >> 11;
#pragma unroll
        for (int fj = 0; fj < 4; ++fj) {
          float xn = acc[fi][fj][r] * rinv * wv[fj];
          float pr = __shfl_xor(xn, 1);
          float rot = (lr & 1) ? pr : -pr;
          int ci = t * 32 + fj * 8 + (lr >> 1);
          u16 outv = f2bf((xn * ctab[ci] + rot * stab[ci]) * sc);
          int n = ncol0 + fj * 16 + lr;
          if (isq) {
            int h = n >> 6, d = n & 63;
            qh[((size_t)((b * 16 + h) * 2048 + t)) * 64 + d] = outv;
          } else {
            int n2 = n - 1024, g = n2 >> 6, d = n2 & 63;
            kh[((size_t)((b * 4 + g) * 2048 + t)) * 64 + d] = outv;
          }
        }
      }
  } else {
#pragma unroll
    for (int fi = 0; fi < 4; ++fi)
#pragma unroll
      for (int fj = 0; fj < 4; ++fj) {
        int m = m0 + wr * 64 + fi * 16 + lk * 4;
        int b = m >> 11, t = m & 2047;
        int n2 = ncol0 + fj * 16 + lr - 1280;
        int g = n2 >> 6, d = n2 & 63;
        bf16x4 o;
#pragma unroll
        for (int r = 0; r < 4; ++r) o[r] = f2bf_cvt(acc[fi][fj][r]);
        int tsw = t ^ (((d >> 3) & 1) * 4);  // pre-swap 8B k-units for odd d>>3
        *reinterpret_cast<bf16x4*>(&vt[((size_t)((b * 4 + g) * 64 + d)) * 2048 + tsw]) = o;
      }
  }
}

// flash attention: 8-wave blocks, GQA head-pair shares one K/V LDS stream.
// KVBLK=64, no softmax bias, conflict-free K/V reads, MFMA(ones) row-sum.
// T4 counted-vmcnt 3-buffer pipeline: per round vmcnt(2) (stage it landed,
// 2 stages stay in flight across barriers) -> barrier -> issue stage(it+2)
// -> compute(it). Literal buf indices via x3 unroll + remainder switch.
__launch_bounds__(512)
__global__ void attn_kernel(const u16* __restrict__ qh, const u16* __restrict__ kh,
                            const u16* __restrict__ vt, u16* __restrict__ ao) {
  __shared__ __align__(16) u16 Ks[3][64 * 64];
  __shared__ __align__(16) u16 Vts[3][64 * 64];
  const int tid = threadIdx.x, w = tid >> 6, l = tid & 63;
  const int lr = l & 15, lk = l >> 4;
  const int wq = w & 3, wh = w >> 2;
  // decode: xcd = D&7 selects (b,g) so all 32 blocks sharing K/V sit on 1 XCD
  const int D = blockIdx.x;
  const int j = D >> 3;
  const int p = j & 15, hp = (j >> 4) & 1;
  const int z = (D & 7) + 8 * (j >> 5);  // z = b*4+g, 0..15
  const int b = z >> 2, g = z & 3;
  const int h = g * 4 + hp * 2 + wh;
  const u16* Qh = qh + ((size_t)((b * 16 + h) * 2048)) * 64;
  const u16* Kb = kh + ((size_t)z * 2048) * 64;
  const u16* Vtb = vt + ((size_t)z * 64) * 2048;
  const int swz = (lr & 7) * 8;  // XOR swizzle in 8-elem (16B) units

  // staging: 512 threads x 16B = one 8KB tile each for K and V^T
  const int r0 = tid >> 3, s0 = ((tid & 7) ^ (r0 & 7)) * 8;
  char* kd = (char*)&Ks[0][0] + (tid & ~63) * 16;
  char* vd = (char*)&Vts[0][0] + (tid & ~63) * 16;
  const u16* kp; const u16* vp;

  auto stage = [&](int buf) {
    __builtin_amdgcn_global_load_lds(GP(kp), LP(kd + buf * 8192), 16, 0, 0);
    __builtin_amdgcn_global_load_lds(GP(vp), LP(vd + buf * 8192), 16, 0, 0);
    kp += 64 * 64; vp += 64;
  };

  // hoisted LDS read base pointers (buf0); fi/db/buf variation is an immediate
  const u16* kbase[2];
  kbase[0] = &Ks[0][lr * 64 + ((lk * 8) ^ swz)];
  kbase[1] = &Ks[0][lr * 64 + ((32 + lk * 8) ^ swz)];
  const u16* vbase[4];
#pragma unroll
  for (int fi = 0; fi < 4; ++fi)
    vbase[fi] = &Vts[0][lr * 64 + (((fi * 16 + lk * 4) ^ swz) ^ ((lr >> 3) * 4))];

  bf16x4 ones;
#pragma unroll
  for (int r = 0; r < 4; ++r) ones[r] = (short)0x3F80;  // bf16 1.0

  auto run_qtile = [&](int qt) {
    const int q0 = qt * 64;
    const int nIt = qt + 1;
    const u16* Qb = Qh + (size_t)(q0 + wq * 16) * 64;
    const bf16x8 qf0 = *reinterpret_cast<const bf16x8*>(&Qb[lr * 64 + lk * 8]);
    const bf16x8 qf1 = *reinterpret_cast<const bf16x8*>(&Qb[lr * 64 + 32 + lk * 8]);
    f32x4 oacc[4] = {};
    f32x4 lacc = {};  // row-sum accumulator via MFMA(ones)
    kp = Kb + r0 * 64 + s0;
    vp = Vtb + (size_t)r0 * 2048 + s0;
    // prologue: barrier (protect buffers from previous q-tile's reads), 2 stages
    __builtin_amdgcn_s_barrier();
    stage(0);
    stage(1);

    // round: vmcnt(N) -> barrier -> [stage(it+2) into bufS] -> compute(buf)
    auto round = [&](int it, const int buf, const int bufS,
                     const bool doStage, const bool last) {
      if (last) asm volatile("s_waitcnt vmcnt(0)" ::: "memory");
      else      asm volatile("s_waitcnt vmcnt(2)" ::: "memory");
      __builtin_amdgcn_s_barrier();
      if (doStage) stage(bufS);
      // QK^T (swapped), zero-init C: sacc[fi][r] = S[k=fi*16+lk*4+r][q=lr]
      f32x4 sacc[4] = {};
      __builtin_amdgcn_s_setprio(1);
#pragma unroll
      for (int kk = 0; kk < 2; ++kk) {
        bf16x8 qf = kk ? qf1 : qf0;
#pragma unroll
        for (int fi = 0; fi < 4; ++fi) {
          bf16x8 kf = *reinterpret_cast<const bf16x8*>(kbase[kk] + buf * 4096 + fi * 1024);
          sacc[fi] = __builtin_amdgcn_mfma_f32_16x16x32_bf16(kf, qf, sacc[fi], 0, 0, 0);
        }
      }
      __builtin_amdgcn_s_setprio(0);
      if (it == qt) {  // causal mask on diagonal tile
        int qloc = wq * 16 + lr;
#pragma unroll
        for (int fi = 0; fi < 4; ++fi)
#pragma unroll
          for (int r = 0; r < 4; ++r)
            if (fi * 16 + lk * 4 + r > qloc) sacc[fi][r] = -1e30f;
      }
      // P = exp2(S); row-sum via MFMA(ones)
      bf16x4 pb[4];
#pragma unroll
      for (int fi = 0; fi < 4; ++fi)
#pragma unroll
        for (int r = 0; r < 4; ++r)
          pb[fi][r] = f2bf_cvt(exp2f(sacc[fi][r]));
      __builtin_amdgcn_s_setprio(1);
#pragma unroll
      for (int fi = 0; fi < 4; ++fi) {
        lacc = MFMA16(ones, pb[fi], lacc);
#pragma unroll
        for (int db = 0; db < 4; ++db) {
          bf16x4 vf = *reinterpret_cast<const bf16x4*>(vbase[fi] + buf * 4096 + db * 1024);
          oacc[db] = MFMA16(vf, pb[fi], oacc[db]);
        }
      }
      __builtin_amdgcn_s_setprio(0);
    };

    int it = 0;
    for (; it + 4 < nIt; it += 3) {          // stages it+2..it+4 all < nIt
      round(it,     0, 2, true,  false);
      round(it + 1, 1, 0, true,  false);
      round(it + 2, 2, 1, true,  false);
    }
    switch (nIt - it) {                       // it % 3 == 0 here
      case 4:
        round(it,     0, 2, true,  false);    // stages nIt-2
        round(it + 1, 1, 0, true,  false);    // stages nIt-1
        round(it + 2, 2, 1, false, false);
        round(it + 3, 0, 0, false, true);
        break;
      case 3:
        round(it,     0, 2, true,  false);    // stages nIt-1
        round(it + 1, 1, 0, false, false);
        round(it + 2, 2, 0, false, true);
        break;
      case 2:
        round(it,     0, 2, false, false);
        round(it + 1, 1, 0, false, true);
        break;
      default:  // 1
        round(it,     0, 0, false, true);
        break;
    }

    // lacc[0] = full row-sum for q=lr (summed over all k incl. lk groups)
    float inv = 1.0f / lacc[0];
#pragma unroll
    for (int db = 0; db < 4; ++db) {
      bf16x4 o;
#pragma unroll
      for (int r = 0; r < 4; ++r) o[r] = f2bf_cvt(oacc[db][r] * inv);
      *reinterpret_cast<bf16x4*>(
          &ao[((size_t)(b * 2048 + q0 + wq * 16 + lr)) * 1024 + h * 64 + db * 16 + lk * 4]) = o;
    }
  };
  run_qtile(31 - p);
  run_qtile(p);
}

// out[M][1024] fp32 = ao[M][1024](bf16) * Wo[1024][1024]^T(bf16), dbuf staging,
// XCD-swizzled 1-D grid: n-panel = bid&7 -> all blocks sharing a Wo panel on 1 XCD
__launch_bounds__(256)
__global__ void gemm_out_kernel(const u16* __restrict__ A, const u16* __restrict__ W,
                                float* __restrict__ out) {
  __shared__ __align__(16) u16 As[2][128 * 64];
  __shared__ __align__(16) u16 Bs[2][128 * 64];
  const int tid = threadIdx.x;
  const int w = tid >> 6, l = tid & 63;
  const int lr = l & 15, lk = l >> 4;
  const int wr = w >> 1, wc = w & 1;
  const int bid = blockIdx.x;
  const int m0 = (bid >> 3) * 128, n0 = (bid & 7) * 128;
  const u16* ap[4];
  const u16* bp[4];
#pragma unroll
  for (int i = 0; i < 4; ++i) {
    int c = i * 256 + tid;
    ap[i] = A + (size_t)(m0 + (c >> 3)) * 1024 + (c & 7) * 8;
    bp[i] = W + (size_t)(n0 + (c >> 3)) * 1024 + (c & 7) * 8;
  }
  auto stage = [&](int buf) {
#pragma unroll
    for (int i = 0; i < 4; ++i) {
      __builtin_amdgcn_global_load_lds(GP(ap[i]),
          LP((char*)&As[0][0] + buf * 16384 + (i * 256 + (tid & ~63)) * 16), 16, 0, 0);
      __builtin_amdgcn_global_load_lds(GP(bp[i]),
          LP((char*)&Bs[0][0] + buf * 16384 + (i * 256 + (tid & ~63)) * 16), 16, 0, 0);
      ap[i] += 64; bp[i] += 64;
    }
  };
  f32x4 acc[4][4] = {};
  int cur = 0;
  stage(0);
  asm volatile("s_waitcnt vmcnt(0)" ::: "memory");
  __builtin_amdgcn_s_barrier();
  for (int k0 = 0; k0 < 1024; k0 += 64) {
    if (k0 < 960) stage(cur ^ 1);
    __builtin_amdgcn_s_setprio(1);
#pragma unroll
    for (int kk = 0; kk < 2; ++kk) {
      bf16x8 af[4], bfr[4];
#pragma unroll
      for (int fi = 0; fi < 4; ++fi)
        af[fi] = *reinterpret_cast<const bf16x8*>(
            &As[cur][(wr * 64 + fi * 16 + lr) * 64 + kk * 32 + lk * 8]);
#pragma unroll
      for (int fj = 0; fj < 4; ++fj)
        bfr[fj] = *reinterpret_cast<const bf16x8*>(
            &Bs[cur][(wc * 64 + fj * 16 + lr) * 64 + kk * 32 + lk * 8]);
#pragma unroll
      for (int fi = 0; fi < 4; ++fi)
#pragma unroll
        for (int fj = 0; fj < 4; ++fj)
          acc[fi][fj] = __builtin_amdgcn_mfma_f32_16x16x32_bf16(af[fi], bfr[fj], acc[fi][fj], 0, 0, 0);
    }
    __builtin_amdgcn_s_setprio(0);
    asm volatile("s_waitcnt vmcnt(0)" ::: "memory");
    __builtin_amdgcn_s_barrier();
    cur ^= 1;
  }
#pragma unroll
  for (int fi = 0; fi < 4; ++fi)
#pragma unroll
    for (int fj = 0; fj < 4; ++fj)
#pragma unroll
      for (int r = 0; r < 4; ++r) {
        int m = m0 + wr * 64 + fi * 16 + lk * 4 + r;
        int n = n0 + wc * 64 + fj * 16 + lr;
        out[(size_t)m * 1024 + n] = acc[fi][fj][r];
      }
}

extern "C" void kernel_launch(void* const* d_in, const int* in_sizes, int n_in,
                              void* d_out, int out_size, void* d_ws, size_t ws_size,
                              hipStream_t stream) {
  const float* x  = (const float*)d_in[0];
  const float* Wq = (const float*)d_in[1];
  const float* Wk = (const float*)d_in[2];
  const float* Wv = (const float*)d_in[3];
  const float* Wo = (const float*)d_in[4];
  const float* qn = (const float*)d_in[5];
  const float* kn = (const float*)d_in[6];
  float* out = (float*)d_out;
  char* ws = (char*)d_ws;
  u16* xb   = (u16*)(ws);                 // 16,777,216
  u16* Wcat = (u16*)(ws + 16777216);      //  3,145,728
  u16* Wob  = (u16*)(ws + 19922944);      //  2,097,152
  u16* qh   = (u16*)(ws + 22020096);      // 16,777,216
  u16* kh   = (u16*)(ws + 38797312);      //  4,194,304
  u16* vtb  = (u16*)(ws + 42991616);      //  4,194,304
  u16* ao   = (u16*)(ws + 47185920);      // 16,777,216 (end 63,963,136)
  float* ctab = (float*)ao;               // overwritten by attn before gemm_out
  float* stab = ctab + 65536;

  prep_kernel<<<2944, 256, 0, stream>>>(x, Wq, Wk, Wv, Wo, xb, Wcat, Wob, ctab, stab);
  dim3 g1(64, 12);
  gemm_qkv_kernel<<<g1, 256, 0, stream>>>(xb, Wcat, qh, kh, vtb, qn, kn, ctab, stab);
  attn_kernel<<<512, 512, 0, stream>>>(qh, kh, vtb, ao);
  gemm_out_kernel<<<512, 256, 0, stream>>>(ao, Wob, out);
}